// Round 12
// baseline (963342.480 us; speedup 1.0000x reference)
//
#include <hip/hip_runtime.h>

using short8 = __attribute__((ext_vector_type(8))) short;
using f32x4  = __attribute__((ext_vector_type(4))) float;

#define NT     512
#define NBATCH 64
#define NN     1024
#define NIN    24
#define NGRP   8
#define BPG    8                        // batches per group
#define NWG    128                      // 2x oversubscription for XCD claiming
#define OBS_BUF_ELEMS (NGRP * BPG * NN) // 64K u16 per ping-pong buffer
#define SCOPE_AGENT __HIP_MEMORY_SCOPE_AGENT

// ws: [0,512) arr u32[128] | [512,576) xcd_cnt u32[16] | [576,580) ovf_cnt
//     [640,704) grp_slow u32[16] | [1024,5120) flags32: 8 grp x 8 slot x 16 u32
//     [5120,8192) zero region | [8192,+256KB) obs 2 x [8 grp][8 rows][1024] bf16

__device__ __forceinline__ unsigned short f2bf(float x) {
  union { float f; unsigned u; } v; v.f = x;
  return (unsigned short)((v.u + 0x7FFFu + ((v.u >> 16) & 1u)) >> 16);
}
__device__ __forceinline__ f32x4 MF(short8 a, short8 b, f32x4 c) {
  return __builtin_amdgcn_mfma_f32_16x16x32_bf16(a, b, c, 0, 0, 0);
}
// out store: sc1 -> bypass L2 (don't evict obs), ack at L3
__device__ __forceinline__ void st_out(float* p, float v) {
  asm volatile("global_store_dword %0, %1, off sc1" :: "v"(p), "v"(v) : "memory");
}

union PK { unsigned u[4]; short8 s; };

// L2-serviced atomic read (bypasses L1, no cache maintenance): old = mem; mem += 0
#define AT_LD(d, OFF) \
  asm volatile("global_atomic_add %0, %1, %2, off offset:" OFF " sc0" \
               : "=v"(d) : "v"(bp), "v"(z32) : "memory")
#define ISSUE_CHUNK(R, C) do { \
  unsigned long long bp = abu + (C) * 256; unsigned z32 = 0u; \
  AT_LD(R[0],"0");   AT_LD(R[1],"4");   AT_LD(R[2],"8");   AT_LD(R[3],"12"); \
  AT_LD(R[4],"64");  AT_LD(R[5],"68");  AT_LD(R[6],"72");  AT_LD(R[7],"76"); \
  AT_LD(R[8],"128"); AT_LD(R[9],"132"); AT_LD(R[10],"136");AT_LD(R[11],"140"); \
  AT_LD(R[12],"192");AT_LD(R[13],"196");AT_LD(R[14],"200");AT_LD(R[15],"204"); \
} while (0)
#define USE_CHUNK(R, C) do { \
  PK p0, p1, p2, p3; \
  p0.u[0]=R[0]; p0.u[1]=R[1]; p0.u[2]=R[2]; p0.u[3]=R[3]; \
  p1.u[0]=R[4]; p1.u[1]=R[5]; p1.u[2]=R[6]; p1.u[3]=R[7]; \
  p2.u[0]=R[8]; p2.u[1]=R[9]; p2.u[2]=R[10];p2.u[3]=R[11]; \
  p3.u[0]=R[12];p3.u[1]=R[13];p3.u[2]=R[14];p3.u[3]=R[15]; \
  acc  = MF(p0.s, wf[(C)*4+0], acc);  acc1 = MF(p1.s, wf[(C)*4+1], acc1); \
  acc  = MF(p2.s, wf[(C)*4+2], acc);  acc1 = MF(p3.s, wf[(C)*4+3], acc1); \
} while (0)
#define VMWAIT(N) do { asm volatile("s_waitcnt vmcnt(" #N ")" ::: "memory"); \
                       __builtin_amdgcn_sched_barrier(0); } while (0)

// 128 WGs x 512 thr (8 waves); 64 become active. Each block claims a slot on
// ITS OWN XCD (atomicAdd on xcd_cnt[XCC_ID]): first 8 per XCD form that XCD's
// group -> co-located by construction. Group g: batches [8g,8g+8); slot owns
// neurons [128*slot,+128). W fragments persistent in registers.
// R11 fast path: obs/flag publish = plain write-through stores into the XCD's
// L2; ALL cross-CU reads = add-0 atomics (bypass L1, serviced at local L2).
// NO buffer_inv (it is wbinv-L2: R6-R10's per-step inv forced the obs exchange
// through L3 = the 6us/step floor). Slow path (deficit groups): R10 agent ops.
__global__ __launch_bounds__(512, 1) void rnn_step_all(
    const float* __restrict__ u, const float* __restrict__ r0,
    const float* __restrict__ W, const float* __restrict__ Bm,
    const float* __restrict__ tau, const float* __restrict__ ds,
    float* __restrict__ out,
    unsigned* __restrict__ arr, unsigned* __restrict__ xcd_cnt,
    unsigned* __restrict__ ovf_cnt, unsigned* __restrict__ grp_slow,
    unsigned* __restrict__ flags32, unsigned short* __restrict__ zreg,
    unsigned short* __restrict__ obs)
{
  const int tid  = threadIdx.x;
  const int wave = tid >> 6;
  const int lane = tid & 63;
  const int bid  = blockIdx.x;
  const int lr = lane & 15, lg = lane >> 4;

  __shared__ unsigned s_g, s_slot, s_mode, s_fast;  // 0=native 1=fallback 2=idle 3=pending

  auto grid_barrier = [&](unsigned epoch) {
    if (tid == 0)
      __hip_atomic_store(&arr[bid], epoch, __ATOMIC_RELEASE, SCOPE_AGENT);
    if (wave == 0) {
      for (;;) {
        unsigned a = __hip_atomic_load(&arr[lane],      __ATOMIC_RELAXED, SCOPE_AGENT);
        unsigned b = __hip_atomic_load(&arr[64 + lane], __ATOMIC_RELAXED, SCOPE_AGENT);
        if (__all((int)(a >= epoch && b >= epoch))) break;
        __builtin_amdgcn_s_sleep(1);
      }
    }
    __syncthreads();
    __builtin_amdgcn_fence(__ATOMIC_ACQUIRE, "agent");
  };

  // ---- claim a slot on my XCD ----
  unsigned myxcc;
  asm volatile("s_getreg_b32 %0, hwreg(HW_REG_XCC_ID)" : "=s"(myxcc));
  if (tid == 0) {
    unsigned c = __hip_atomic_fetch_add(&xcd_cnt[myxcc & 7], 1u,
                                        __ATOMIC_RELAXED, SCOPE_AGENT);
    if (c < 8) { s_g = myxcc & 7; s_slot = c; s_mode = 0; }
    else {
      s_g = __hip_atomic_fetch_add(ovf_cnt, 1u, __ATOMIC_RELAXED, SCOPE_AGENT);
      s_slot = 0; s_mode = 3;
    }
  }
  __syncthreads();
  grid_barrier(1);

  // ---- overflow blocks resolve deficits deterministically ----
  if (s_mode == 3) {
    if (tid == 0) {
      unsigned k = s_g, base = 0, mode = 2, g = 0, slot = 0;
      for (int gg = 0; gg < 8; ++gg) {
        unsigned c = __hip_atomic_load(&xcd_cnt[gg], __ATOMIC_RELAXED, SCOPE_AGENT);
        unsigned have = c < 8 ? c : 8;
        unsigned def  = 8 - have;
        if (k < base + def) { g = gg; slot = have + (k - base); mode = 1; break; }
        base += def;
      }
      s_g = g; s_slot = slot; s_mode = mode;
      if (mode == 1)
        __hip_atomic_store(&grp_slow[g], 1u, __ATOMIC_RELAXED, SCOPE_AGENT);
    }
    __syncthreads();
  }
  grid_barrier(2);
  if (s_mode == 2) return;

  if (tid == 0) {
    unsigned sl = __hip_atomic_load(&grp_slow[s_g], __ATOMIC_RELAXED, SCOPE_AGENT);
    s_fast = (s_mode == 0 && sl == 0u) ? 1u : 0u;
  }
  __syncthreads();
  const int  g    = (int)s_g;
  const int  slot = (int)s_slot;
  const bool fast = s_fast != 0;

  const int b0 = g * BPG;
  const int i  = slot * 128 + wave * 16 + lr;   // this lane's neuron

  unsigned* gfl = flags32 + g * 128;            // 8 slots x 16 u32 (64B apart)

  // ---- persistent W fragments: B[k][col] = W[i0+col][kb*32+k]*sign ----
  short8 wf[32];
#pragma unroll
  for (int kb = 0; kb < 32; ++kb) {
    const int j0 = kb * 32 + lg * 8;
    const float* wp = W + (size_t)i * NN + j0;
    f32x4 w0 = *(const f32x4*)(wp);
    f32x4 w1 = *(const f32x4*)(wp + 4);
    f32x4 s0 = *(const f32x4*)(ds + j0);
    f32x4 s1 = *(const f32x4*)(ds + j0 + 4);
    short8 f;
    f[0] = (short)f2bf(w0[0] * s0[0]); f[1] = (short)f2bf(w0[1] * s0[1]);
    f[2] = (short)f2bf(w0[2] * s0[2]); f[3] = (short)f2bf(w0[3] * s0[3]);
    f[4] = (short)f2bf(w1[0] * s1[0]); f[5] = (short)f2bf(w1[1] * s1[1]);
    f[6] = (short)f2bf(w1[2] * s1[2]); f[7] = (short)f2bf(w1[3] * s1[3]);
    wf[kb] = f;
  }
  short8 bin;
#pragma unroll
  for (int e = 0; e < 8; ++e) {
    const int m = lg * 8 + e;
    bin[e] = (short)f2bf(m < NIN ? Bm[(size_t)i * NIN + m] : 0.0f);
  }
  const float itau = 1.0f / tau[i];

  unsigned short* owbuf0 = obs + g * BPG * NN;
  unsigned short* owbuf1 = owbuf0 + OBS_BUF_ELEMS;

  // ---- init r; publish obs buf0; flag epoch 1 ----
  f32x4 r = {0.f, 0.f, 0.f, 0.f};
  if (lg < 2) {
#pragma unroll
    for (int q = 0; q < 4; ++q) {
      const int row = lg * 4 + q;
      r[q] = r0[(size_t)(b0 + row) * NN + i];
      const unsigned short v = f2bf(r[q] > 0.0f ? r[q] : 0.0f);
      if (fast) owbuf0[row * NN + i] = v;
      else      __hip_atomic_store(&owbuf0[row * NN + i], v,
                                   __ATOMIC_RELAXED, SCOPE_AGENT);
    }
  }
  asm volatile("s_waitcnt vmcnt(0)" ::: "memory");
  __syncthreads();
  if (tid == 0) {
    if (fast) *(volatile unsigned*)&gfl[slot * 16] = 1u;
    else      __hip_atomic_store(&gfl[slot * 16], 1u, __ATOMIC_RELAXED, SCOPE_AGENT);
  }

  const float* up_base = u + (size_t)(b0 + lr) * NT * NIN;
  f32x4 up0 = {0.f,0.f,0.f,0.f}, up1 = {0.f,0.f,0.f,0.f};
  if (lr < 8 && lg < 3) {
    up0 = *(const f32x4*)(up_base + lg * 8);
    up1 = *(const f32x4*)(up_base + lg * 8 + 4);
  }

  // poll: fast -> add-0 atomic at local L2 (bypasses L1, always fresh, no inv);
  //       slow -> agent atomic (L3) + acquire fence.
  auto group_wait = [&](unsigned tgt) {
    if (wave == 0) {
      if (fast) {
        for (;;) {
          unsigned x = 0xFFFFFFFFu;
          if (lane < 8) {
            unsigned long long bp = (unsigned long long)(gfl + lane * 16);
            unsigned z32 = 0u;
            asm volatile("global_atomic_add %0, %1, %2, off sc0\n\t"
                         "s_waitcnt vmcnt(0)"
                         : "=v"(x) : "v"(bp), "v"(z32) : "memory");
          }
          if (__all((int)(x >= tgt))) break;
          __builtin_amdgcn_s_sleep(1);
        }
      } else {
        for (;;) {
          unsigned x = __hip_atomic_load(&gfl[(lane & 7) * 16],
                                         __ATOMIC_RELAXED, SCOPE_AGENT);
          if (__all((int)(x >= tgt))) break;
          __builtin_amdgcn_s_sleep(1);
        }
      }
    }
    __syncthreads();
    if (!fast) __builtin_amdgcn_fence(__ATOMIC_ACQUIRE, "agent");
  };

  group_wait(1);

  // per-lane A base: rows >= 8 of the 16x16 A tile read the zero region
  const unsigned short* ab0 = (lr < 8) ? owbuf0 + lr * NN + lg * 8 : zreg + lg * 8;
  const unsigned short* ab1 = (lr < 8) ? ab0 + OBS_BUF_ELEMS : ab0;

  for (int t = 0; t < NT; ++t) {
    const unsigned short* ab = (t & 1) ? ab1 : ab0;
    unsigned short*       ow = (t & 1) ? owbuf0 : owbuf1;

    f32x4 acc  = {0.f, 0.f, 0.f, 0.f};
    f32x4 acc1 = {0.f, 0.f, 0.f, 0.f};

    // input term: A[row=lr][m] = u[b0+lr][t][m], zero-padded
    short8 ua;
    ua[0] = (short)f2bf(up0[0]); ua[1] = (short)f2bf(up0[1]);
    ua[2] = (short)f2bf(up0[2]); ua[3] = (short)f2bf(up0[3]);
    ua[4] = (short)f2bf(up1[0]); ua[5] = (short)f2bf(up1[1]);
    ua[6] = (short)f2bf(up1[2]); ua[7] = (short)f2bf(up1[3]);
    if (lr >= 8 || lg >= 3) ua = short8{0,0,0,0,0,0,0,0};
    acc = MF(ua, bin, acc);

    if (fast) {
      // recurrent GEMM: 512B/lane as add-0 atomics at the local L2,
      // 3-deep chunk pipeline with counted vmcnt (8 chunks x 16 dwords)
      const unsigned long long abu = (unsigned long long)ab;
      unsigned Ra[16], Rb[16], Rc[16];
      ISSUE_CHUNK(Ra, 0); ISSUE_CHUNK(Rb, 1);
      ISSUE_CHUNK(Rc, 2); VMWAIT(32); USE_CHUNK(Ra, 0);
      ISSUE_CHUNK(Ra, 3); VMWAIT(32); USE_CHUNK(Rb, 1);
      ISSUE_CHUNK(Rb, 4); VMWAIT(32); USE_CHUNK(Rc, 2);
      ISSUE_CHUNK(Rc, 5); VMWAIT(32); USE_CHUNK(Ra, 3);
      ISSUE_CHUNK(Ra, 6); VMWAIT(32); USE_CHUNK(Rb, 4);
      ISSUE_CHUNK(Rb, 7); VMWAIT(32); USE_CHUNK(Rc, 5);
                          VMWAIT(16); USE_CHUNK(Ra, 6);
                          VMWAIT(0);  USE_CHUNK(Rb, 7);
    } else {
#pragma unroll
      for (int kb = 0; kb < 32; kb += 2) {
        short8 a0 = *(const short8*)(ab + kb * 32);
        short8 a1 = *(const short8*)(ab + kb * 32 + 32);
        acc  = MF(a0, wf[kb],     acc);
        acc1 = MF(a1, wf[kb + 1], acc1);
      }
    }

    // state update
    f32x4 rv;
#pragma unroll
    for (int q = 0; q < 4; ++q) {
      const float pre = acc[q] + acc1[q];
      const float act = 60.0f / (1.0f + expf(8.4f - 0.28f * pre)); // 30*(1+tanh(.14x-4.2))
      rv[q] = r[q] + (0.1f * (act - r[q])) * itau;
      r[q]  = rv[q];
    }

    if (t != NT - 1) {
      // release: obs stores -> vmcnt(0) (L2 ack) -> barrier -> flag store
      if (lg < 2) {
#pragma unroll
        for (int q = 0; q < 4; ++q) {
          const unsigned short v = f2bf(rv[q] > 0.0f ? rv[q] : 0.0f);
          if (fast) ow[(lg * 4 + q) * NN + i] = v;
          else      __hip_atomic_store(&ow[(lg * 4 + q) * NN + i], v,
                                       __ATOMIC_RELAXED, SCOPE_AGENT);
        }
      }
      asm volatile("s_waitcnt vmcnt(0)" ::: "memory");
      __syncthreads();
      if (tid == 0) {
        if (fast) *(volatile unsigned*)&gfl[slot * 16] = (unsigned)(t + 2);
        else      __hip_atomic_store(&gfl[slot * 16], (unsigned)(t + 2),
                                     __ATOMIC_RELAXED, SCOPE_AGENT);
      }

      // off-critical-path (drains during the poll): u prefetch, out stores
      if (lr < 8 && lg < 3) {
        const float* up = up_base + (t + 1) * NIN + lg * 8;
        up0 = *(const f32x4*)(up);
        up1 = *(const f32x4*)(up + 4);
      }
      if (lg < 2) {
#pragma unroll
        for (int q = 0; q < 4; ++q)
          st_out(&out[((size_t)(b0 + lg * 4 + q) * NT + t) * NN + i], rv[q]);
      }

      group_wait((unsigned)(t + 2));
    } else {
      if (lg < 2) {
#pragma unroll
        for (int q = 0; q < 4; ++q)
          st_out(&out[((size_t)(b0 + lg * 4 + q) * NT + t) * NN + i], rv[q]);
      }
    }
  }

  // r_final
  if (lg < 2) {
#pragma unroll
    for (int q = 0; q < 4; ++q)
      out[(size_t)NBATCH * NT * NN + (size_t)(b0 + lg * 4 + q) * NN + i] = r[q];
  }
}

extern "C" void kernel_launch(void* const* d_in, const int* in_sizes, int n_in,
                              void* d_out, int out_size, void* d_ws, size_t ws_size,
                              hipStream_t stream) {
  const float* u   = (const float*)d_in[0];
  const float* r0  = (const float*)d_in[1];
  const float* W   = (const float*)d_in[2];
  const float* Bm  = (const float*)d_in[3];
  const float* tau = (const float*)d_in[4];
  const float* ds  = (const float*)d_in[5];
  float* out = (float*)d_out;

  unsigned*       arr      = (unsigned*)d_ws;
  unsigned*       xcd_cnt  = (unsigned*)((char*)d_ws + 512);
  unsigned*       ovf_cnt  = (unsigned*)((char*)d_ws + 576);
  unsigned*       grp_slow = (unsigned*)((char*)d_ws + 640);
  unsigned*       flags32  = (unsigned*)((char*)d_ws + 1024);
  unsigned short* zreg     = (unsigned short*)((char*)d_ws + 5120);
  unsigned short* obs      = (unsigned short*)((char*)d_ws + 8192);

  // zero all control state every call (incl. graph replays -> deterministic)
  hipMemsetAsync(d_ws, 0, 8192, stream);

  rnn_step_all<<<dim3(NWG), dim3(512), 0, stream>>>(u, r0, W, Bm, tau, ds, out,
                                                    arr, xcd_cnt, ovf_cnt, grp_slow,
                                                    flags32, zreg, obs);
}

// Round 13
// 4560.004 us; speedup vs baseline: 211.2591x; 211.2591x over previous
//
#include <hip/hip_runtime.h>

using short8 = __attribute__((ext_vector_type(8))) short;
using f32x4  = __attribute__((ext_vector_type(4))) float;
using uint4v = __attribute__((ext_vector_type(4))) unsigned;

#define NT     512
#define NBATCH 64
#define NN     1024
#define NIN    24
#define NG     4                    // sync groups of 16 batches
#define NSLOT  8                    // neuron slots (128 neurons each)
#define OBS_BUF (NG * 16 * NN)      // u16 elems per ping-pong buffer
#define SCOPE_AGENT __HIP_MEMORY_SCOPE_AGENT

// ws: [0,4096) flags u32[NG*NSLOT*16] (64B apart) | [8192,+256KB) obs ping-pong

__device__ __forceinline__ unsigned short f2bf(float x) {
  union { float f; unsigned u; } v; v.f = x;
  return (unsigned short)((v.u + 0x7FFFu + ((v.u >> 16) & 1u)) >> 16);
}
__device__ __forceinline__ f32x4 MF(short8 a, short8 b, f32x4 c) {
  return __builtin_amdgcn_mfma_f32_16x16x32_bf16(a, b, c, 0, 0, 0);
}

// obs A-loads: bypass L1/L2, read at L3 (the only coherence point reachable
// from HIP for cross-XCD data — R4-R11 established L2-local exchange is not).
// All asm carries "memory" so the compiler cannot interleave its own VMEM
// into the counted-vmcnt region.
#define LD16(d, bp, OFF) \
  asm volatile("global_load_dwordx4 %0, %1, off offset:" OFF " sc0 sc1" \
               : "=v"(d) : "v"(bp) : "memory")
#define ISSUE(Rq, C) do { const unsigned short* bp_ = ab + (C) * 128; \
  LD16(Rq[0], bp_, "0"); LD16(Rq[1], bp_, "64"); \
  LD16(Rq[2], bp_, "128"); LD16(Rq[3], bp_, "192"); } while (0)
#define USE(Rq, C) do { \
  acc  = MF(*(short8*)&Rq[0], wf[(C)*4+0], acc); \
  acc1 = MF(*(short8*)&Rq[1], wf[(C)*4+1], acc1); \
  acc  = MF(*(short8*)&Rq[2], wf[(C)*4+2], acc); \
  acc1 = MF(*(short8*)&Rq[3], wf[(C)*4+3], acc1); } while (0)
#define VMWAIT(N) do { asm volatile("s_waitcnt vmcnt(" #N ")" ::: "memory"); \
                       __builtin_amdgcn_sched_barrier(0); } while (0)

// 32 blocks x 512 thr (8 waves). Group g = bid&3 owns batches [16g,16g+16);
// slot = bid>>2 owns neurons [128*slot,+128); wave w owns 16 of them.
// A-tiles are FULLY VALID (16 batch rows = 16 MFMA rows, no padding).
// W fragments persistent in registers. Placement-independent; no fences; no
// cache-maintenance ops; all cross-CU traffic rides L3 via sc1.
__global__ __launch_bounds__(512, 1) void rnn_step_all(
    const float* __restrict__ u, const float* __restrict__ r0,
    const float* __restrict__ W, const float* __restrict__ Bm,
    const float* __restrict__ tau, const float* __restrict__ ds,
    float* __restrict__ out,
    unsigned* __restrict__ flags, unsigned short* __restrict__ obs)
{
  const int tid  = threadIdx.x;
  const int wave = tid >> 6;
  const int lane = tid & 63;
  const int bid  = blockIdx.x;
  const int g    = bid & 3;
  const int slot = bid >> 2;
  const int b0   = g * 16;
  const int lr = lane & 15, lg = lane >> 4;
  const int i  = slot * 128 + wave * 16 + lr;   // this lane's neuron

  unsigned* gfl = flags + g * NSLOT * 16;       // 8 slots x 16 u32 (64B apart)

  // ---- persistent W fragments: B[k][col] = W[i0+col][kb*32+k]*sign ----
  short8 wf[32];
#pragma unroll
  for (int kb = 0; kb < 32; ++kb) {
    const int j0 = kb * 32 + lg * 8;
    const float* wp = W + (size_t)i * NN + j0;
    f32x4 w0 = *(const f32x4*)(wp);
    f32x4 w1 = *(const f32x4*)(wp + 4);
    f32x4 s0 = *(const f32x4*)(ds + j0);
    f32x4 s1 = *(const f32x4*)(ds + j0 + 4);
    short8 f;
    f[0] = (short)f2bf(w0[0] * s0[0]); f[1] = (short)f2bf(w0[1] * s0[1]);
    f[2] = (short)f2bf(w0[2] * s0[2]); f[3] = (short)f2bf(w0[3] * s0[3]);
    f[4] = (short)f2bf(w1[0] * s1[0]); f[5] = (short)f2bf(w1[1] * s1[1]);
    f[6] = (short)f2bf(w1[2] * s1[2]); f[7] = (short)f2bf(w1[3] * s1[3]);
    wf[kb] = f;
  }
  short8 bin;
#pragma unroll
  for (int e = 0; e < 8; ++e) {
    const int m = lg * 8 + e;
    bin[e] = (short)f2bf(m < NIN ? Bm[(size_t)i * NIN + m] : 0.0f);
  }
  const float itau = 1.0f / tau[i];

  unsigned short* buf0 = obs + g * 16 * NN;     // this group's tile, buffer 0
  unsigned short* buf1 = buf0 + OBS_BUF;

  // ---- init r (C/D: row(batch)=lg*4+q, col=lr); publish obs buf0 ----
  f32x4 r;
#pragma unroll
  for (int q = 0; q < 4; ++q) {
    const int row = lg * 4 + q;                 // batch row 0..15, all valid
    r[q] = r0[(size_t)(b0 + row) * NN + i];
    __hip_atomic_store(&buf0[row * NN + i], f2bf(r[q] > 0.0f ? r[q] : 0.0f),
                       __ATOMIC_RELAXED, SCOPE_AGENT);
  }
  asm volatile("s_waitcnt vmcnt(0)" ::: "memory");
  __syncthreads();
  if (tid == 0)
    __hip_atomic_store(&gfl[slot * 16], 1u, __ATOMIC_RELAXED, SCOPE_AGENT);

  const float* up_base = u + (size_t)(b0 + lr) * NT * NIN;
  f32x4 up0 = {0.f,0.f,0.f,0.f}, up1 = {0.f,0.f,0.f,0.f};
  if (lg < 3) {
    up0 = *(const f32x4*)(up_base + lg * 8);
    up1 = *(const f32x4*)(up_base + lg * 8 + 4);
  }

  // poll (wave 0, lanes 0-7; busy): proven agent-atomic loads, always fresh.
  // After barrier, ALL waves drain vmcnt so the counted A-pipeline is exact.
  auto group_wait = [&](unsigned tgt) {
    if (wave == 0) {
      for (;;) {
        unsigned x = (lane < 8)
            ? __hip_atomic_load(&gfl[lane * 16], __ATOMIC_RELAXED, SCOPE_AGENT)
            : 0xFFFFFFFFu;
        if (__all((int)(x >= tgt))) break;
      }
    }
    __syncthreads();
    asm volatile("s_waitcnt vmcnt(0)" ::: "memory");
    __builtin_amdgcn_sched_barrier(0);
  };

  group_wait(1);

  for (int t = 0; t < NT; ++t) {
    const unsigned short* ob = (t & 1) ? buf1 : buf0;
    unsigned short*       ow = (t & 1) ? buf0 : buf1;

    f32x4 acc  = {0.f, 0.f, 0.f, 0.f};
    f32x4 acc1 = {0.f, 0.f, 0.f, 0.f};

    // input term first (consumes compiler-loaded up0/up1 so the compiler's
    // waitcnt lands BEFORE the counted region)
    short8 ua;
    ua[0] = (short)f2bf(up0[0]); ua[1] = (short)f2bf(up0[1]);
    ua[2] = (short)f2bf(up0[2]); ua[3] = (short)f2bf(up0[3]);
    ua[4] = (short)f2bf(up1[0]); ua[5] = (short)f2bf(up1[1]);
    ua[6] = (short)f2bf(up1[2]); ua[7] = (short)f2bf(up1[3]);
    if (lg >= 3) ua = short8{0,0,0,0,0,0,0,0};
    acc = MF(ua, bin, acc);

    // recurrent GEMM: 512B/lane sc1 loads from L3, 3-deep counted pipeline
    // (8 chunks x 4 dwordx4; all A rows valid)
    const unsigned short* ab = ob + lr * NN + lg * 8;
    uint4v Ra[4], Rb[4], Rc[4];
    ISSUE(Ra, 0); ISSUE(Rb, 1);
    ISSUE(Rc, 2); VMWAIT(8); USE(Ra, 0);
    ISSUE(Ra, 3); VMWAIT(8); USE(Rb, 1);
    ISSUE(Rb, 4); VMWAIT(8); USE(Rc, 2);
    ISSUE(Rc, 5); VMWAIT(8); USE(Ra, 3);
    ISSUE(Ra, 6); VMWAIT(8); USE(Rb, 4);
    ISSUE(Rb, 7); VMWAIT(8); USE(Rc, 5);
                  VMWAIT(4); USE(Ra, 6);
                  VMWAIT(0); USE(Rb, 7);

    // state update
    f32x4 rv;
#pragma unroll
    for (int q = 0; q < 4; ++q) {
      const float pre = acc[q] + acc1[q];
      const float act = 60.0f / (1.0f + expf(8.4f - 0.28f * pre)); // 30*(1+tanh(.14x-4.2))
      rv[q] = r[q] + (0.1f * (act - r[q])) * itau;
      r[q]  = rv[q];
    }

    if (t != NT - 1) {
      // release: obs agent stores -> vmcnt(0) -> barrier -> one flag store
#pragma unroll
      for (int q = 0; q < 4; ++q)
        __hip_atomic_store(&ow[(lg * 4 + q) * NN + i],
                           f2bf(rv[q] > 0.0f ? rv[q] : 0.0f),
                           __ATOMIC_RELAXED, SCOPE_AGENT);
      asm volatile("s_waitcnt vmcnt(0)" ::: "memory");
      __syncthreads();
      if (tid == 0)
        __hip_atomic_store(&gfl[slot * 16], (unsigned)(t + 2),
                           __ATOMIC_RELAXED, SCOPE_AGENT);

      // off-critical-path (drains during the poll): u prefetch + out stores
      if (lg < 3) {
        const float* up = up_base + (t + 1) * NIN + lg * 8;
        up0 = *(const f32x4*)(up);
        up1 = *(const f32x4*)(up + 4);
      }
#pragma unroll
      for (int q = 0; q < 4; ++q)
        out[((size_t)(b0 + lg * 4 + q) * NT + t) * NN + i] = rv[q];

      group_wait((unsigned)(t + 2));
    } else {
#pragma unroll
      for (int q = 0; q < 4; ++q)
        out[((size_t)(b0 + lg * 4 + q) * NT + t) * NN + i] = rv[q];
    }
  }

  // r_final
#pragma unroll
  for (int q = 0; q < 4; ++q)
    out[(size_t)NBATCH * NT * NN + (size_t)(b0 + lg * 4 + q) * NN + i] = r[q];
}

extern "C" void kernel_launch(void* const* d_in, const int* in_sizes, int n_in,
                              void* d_out, int out_size, void* d_ws, size_t ws_size,
                              hipStream_t stream) {
  const float* u   = (const float*)d_in[0];
  const float* r0  = (const float*)d_in[1];
  const float* W   = (const float*)d_in[2];
  const float* Bm  = (const float*)d_in[3];
  const float* tau = (const float*)d_in[4];
  const float* ds  = (const float*)d_in[5];
  float* out = (float*)d_out;

  unsigned*       flags = (unsigned*)d_ws;
  unsigned short* obs   = (unsigned short*)((char*)d_ws + 8192);

  // zero flag region every call (incl. graph replays -> deterministic)
  hipMemsetAsync(d_ws, 0, 8192, stream);

  rnn_step_all<<<dim3(NG * NSLOT), dim3(512), 0, stream>>>(u, r0, W, Bm, tau, ds,
                                                           out, flags, obs);
}

// Round 14
// 1995.364 us; speedup vs baseline: 482.7904x; 2.2853x over previous
//
#include <hip/hip_runtime.h>

using short8 = __attribute__((ext_vector_type(8))) short;
using f32x4  = __attribute__((ext_vector_type(4))) float;
using uint4v = __attribute__((ext_vector_type(4))) unsigned;

#define NT     512
#define NBATCH 64
#define NN     1024
#define NIN    24
#define NG     4                      // groups of 16 batches
#define NSLOT  8                      // 128 neurons per slot-block
#define ROWS   16
#define OBS32  (NG * ROWS * NN)       // u32 per ping-pong buffer (256 KB)
#define SCOPE_AGENT __HIP_MEMORY_SCOPE_AGENT
#define RETRY_CAP (1 << 17)           // fail loud (absmax), never hang

// ws: [0, 512KB) obs32: 2 ping-pong buffers of {bf16 value | epoch16<<16} words.
// Epoch-in-data sync: producers agent-store tagged words; consumers poll the
// words themselves with sc1 loads until every epoch matches. No flags, no
// fences, no cache-maintenance ops (R4-R12: inv/fences force L3 round-trips;
// atomics-as-loads go memory-side; sc1 loads are uncached -> stage into LDS
// ONCE per block and let all 8 waves read fragments from LDS).

__device__ __forceinline__ unsigned short f2bf(float x) {
  union { float f; unsigned u; } v; v.f = x;
  return (unsigned short)((v.u + 0x7FFFu + ((v.u >> 16) & 1u)) >> 16);
}
__device__ __forceinline__ f32x4 MF(short8 a, short8 b, f32x4 c) {
  return __builtin_amdgcn_mfma_f32_16x16x32_bf16(a, b, c, 0, 0, 0);
}

// 32 blocks x 512 thr (8 waves). Group g = bid&3 owns batches [16g,+16);
// slot = bid>>2 owns neurons [128*slot,+128); wave w owns 16 of them.
// W fragments persistent in registers (128 VGPR). Placement-independent.
__global__ __launch_bounds__(512, 1) void rnn_step_all(
    const float* __restrict__ u, const float* __restrict__ r0,
    const float* __restrict__ W, const float* __restrict__ Bm,
    const float* __restrict__ tau, const float* __restrict__ ds,
    float* __restrict__ out, unsigned* __restrict__ obs32)
{
  __shared__ unsigned long long lds64[ROWS * 2048 / 8];  // 32 KB staged A-tile
  char* ldsb = (char*)lds64;

  const int tid  = threadIdx.x;
  const int wave = tid >> 6;
  const int lane = tid & 63;
  const int bid  = blockIdx.x;
  const int g    = bid & 3;
  const int slot = bid >> 2;
  const int b0   = g * ROWS;
  const int lr = lane & 15, lg = lane >> 4;
  const int i  = slot * 128 + wave * 16 + lr;   // this lane's neuron

  // loader assignment: thread covers row mrow, u32 cols [4*mc + 128*m]
  const int mrow = tid >> 5;                    // 0..15
  const int mc   = tid & 31;                    // 0..31

  // ---- persistent W fragments: B[k][col] = W[i0+col][kb*32+k]*sign ----
  short8 wf[32];
#pragma unroll
  for (int kb = 0; kb < 32; ++kb) {
    const int j0 = kb * 32 + lg * 8;
    const float* wp = W + (size_t)i * NN + j0;
    f32x4 w0 = *(const f32x4*)(wp);
    f32x4 w1 = *(const f32x4*)(wp + 4);
    f32x4 s0 = *(const f32x4*)(ds + j0);
    f32x4 s1 = *(const f32x4*)(ds + j0 + 4);
    short8 f;
    f[0] = (short)f2bf(w0[0] * s0[0]); f[1] = (short)f2bf(w0[1] * s0[1]);
    f[2] = (short)f2bf(w0[2] * s0[2]); f[3] = (short)f2bf(w0[3] * s0[3]);
    f[4] = (short)f2bf(w1[0] * s1[0]); f[5] = (short)f2bf(w1[1] * s1[1]);
    f[6] = (short)f2bf(w1[2] * s1[2]); f[7] = (short)f2bf(w1[3] * s1[3]);
    wf[kb] = f;
  }
  short8 bin;
#pragma unroll
  for (int e = 0; e < 8; ++e) {
    const int m = lg * 8 + e;
    bin[e] = (short)f2bf(m < NIN ? Bm[(size_t)i * NIN + m] : 0.0f);
  }
  const float itau = 1.0f / tau[i];

  unsigned* gt0 = obs32 + g * (ROWS * NN);          // parity-0 tile (this group)
  unsigned* gt1 = obs32 + OBS32 + g * (ROWS * NN);  // parity-1 tile

  // poll + validate + stage into LDS (all 512 threads; 64 KB -> 32 KB)
  auto stage = [&](const unsigned* gtile, unsigned tag) {
    const unsigned* gp = gtile + mrow * NN + mc * 4;
    uint4v R0, R1, R2, R3, R4, R5, R6, R7;
    int guard = 0;
    for (;;) {
      asm volatile(
          "global_load_dwordx4 %0, %8, off sc0 sc1\n\t"
          "global_load_dwordx4 %1, %8, off offset:512 sc0 sc1\n\t"
          "global_load_dwordx4 %2, %8, off offset:1024 sc0 sc1\n\t"
          "global_load_dwordx4 %3, %8, off offset:1536 sc0 sc1\n\t"
          "global_load_dwordx4 %4, %8, off offset:2048 sc0 sc1\n\t"
          "global_load_dwordx4 %5, %8, off offset:2560 sc0 sc1\n\t"
          "global_load_dwordx4 %6, %8, off offset:3072 sc0 sc1\n\t"
          "global_load_dwordx4 %7, %8, off offset:3584 sc0 sc1\n\t"
          "s_waitcnt vmcnt(0)"
          : "=&v"(R0), "=&v"(R1), "=&v"(R2), "=&v"(R3),
            "=&v"(R4), "=&v"(R5), "=&v"(R6), "=&v"(R7)
          : "v"(gp) : "memory");
      unsigned bad = 0;
#define CK(Rx) bad |= ((Rx[0] >> 16) ^ tag) | ((Rx[1] >> 16) ^ tag) | \
                      ((Rx[2] >> 16) ^ tag) | ((Rx[3] >> 16) ^ tag)
      CK(R0); CK(R1); CK(R2); CK(R3); CK(R4); CK(R5); CK(R6); CK(R7);
#undef CK
      if (__all((int)(bad == 0))) break;
      if (++guard > RETRY_CAP) break;   // fail loud, never hang
    }
    const int rbm = (mrow & 7) << 4;
    char* wrow = ldsb + mrow * 2048;
#define WR(Rx, m) do { \
      unsigned lo = (Rx[0] & 0xFFFFu) | (Rx[1] << 16); \
      unsigned hi = (Rx[2] & 0xFFFFu) | (Rx[3] << 16); \
      *(unsigned long long*)(wrow + (((m) * 256 + 8 * mc) ^ rbm)) = \
          ((unsigned long long)hi << 32) | (unsigned long long)lo; \
    } while (0)
    WR(R0, 0); WR(R1, 1); WR(R2, 2); WR(R3, 3);
    WR(R4, 4); WR(R5, 5); WR(R6, 6); WR(R7, 7);
#undef WR
  };

  // ---- init r (C/D: row(batch)=lg*4+q, col=lr); publish r0 obs, tag 1 ----
  f32x4 r;
#pragma unroll
  for (int q = 0; q < 4; ++q) {
    const int row = lg * 4 + q;
    r[q] = r0[(size_t)(b0 + row) * NN + i];
    const unsigned vv = (unsigned)f2bf(r[q] > 0.0f ? r[q] : 0.0f) | (1u << 16);
    __hip_atomic_store(&gt0[row * NN + i], vv, __ATOMIC_RELAXED, SCOPE_AGENT);
  }

  const float* up_base = u + (size_t)(b0 + lr) * NT * NIN;
  f32x4 up0 = {0.f,0.f,0.f,0.f}, up1 = {0.f,0.f,0.f,0.f};
  if (lg < 3) {
    up0 = *(const f32x4*)(up_base + lg * 8);
    up1 = *(const f32x4*)(up_base + lg * 8 + 4);
  }

  stage(gt0, 1u);
  __syncthreads();

  const char* lrow = ldsb + lr * 2048;
  const int rbc = (lr & 7) << 4;

  for (int t = 0; t < NT; ++t) {
    f32x4 acc  = {0.f, 0.f, 0.f, 0.f};
    f32x4 acc1 = {0.f, 0.f, 0.f, 0.f};

    // input term: A[row=lr][m] = u[b0+lr][t][m], zero-padded
    short8 ua;
    ua[0] = (short)f2bf(up0[0]); ua[1] = (short)f2bf(up0[1]);
    ua[2] = (short)f2bf(up0[2]); ua[3] = (short)f2bf(up0[3]);
    ua[4] = (short)f2bf(up1[0]); ua[5] = (short)f2bf(up1[1]);
    ua[6] = (short)f2bf(up1[2]); ua[7] = (short)f2bf(up1[3]);
    if (lg >= 3) ua = short8{0,0,0,0,0,0,0,0};
    acc = MF(ua, bin, acc);

    // recurrent GEMM: A fragments from the swizzled LDS tile (shared by 8 waves)
#pragma unroll
    for (int kb = 0; kb < 32; kb += 2) {
      short8 a0 = *(const short8*)(lrow + ((kb * 64 + lg * 16) ^ rbc));
      short8 a1 = *(const short8*)(lrow + (((kb + 1) * 64 + lg * 16) ^ rbc));
      acc  = MF(a0, wf[kb],     acc);
      acc1 = MF(a1, wf[kb + 1], acc1);
    }

    // state update
    f32x4 rv;
#pragma unroll
    for (int q = 0; q < 4; ++q) {
      const float pre = acc[q] + acc1[q];
      const float act = 60.0f / (1.0f + expf(8.4f - 0.28f * pre)); // 30*(1+tanh(.14x-4.2))
      rv[q] = r[q] + (0.1f * (act - r[q])) * itau;
      r[q]  = rv[q];
    }

    if (t != NT - 1) {
      // publish tagged obs (fire-and-forget agent stores; no vmcnt, no flags)
      const unsigned tag2 = (unsigned)(t + 2);
      unsigned* gw = ((t + 1) & 1) ? gt1 : gt0;
#pragma unroll
      for (int q = 0; q < 4; ++q) {
        const unsigned vv =
            (unsigned)f2bf(rv[q] > 0.0f ? rv[q] : 0.0f) | (tag2 << 16);
        __hip_atomic_store(&gw[(lg * 4 + q) * NN + i], vv,
                           __ATOMIC_RELAXED, SCOPE_AGENT);
      }

      // off-critical-path: out stores + u prefetch (drain inside stage's wait)
#pragma unroll
      for (int q = 0; q < 4; ++q)
        out[((size_t)(b0 + lg * 4 + q) * NT + t) * NN + i] = rv[q];
      if (lg < 3) {
        const float* up = up_base + (t + 1) * NIN + lg * 8;
        up0 = *(const f32x4*)(up);
        up1 = *(const f32x4*)(up + 4);
      }

      __syncthreads();          // all waves done reading the old LDS tile
      stage(gw, tag2);          // poll-validate-stage the next tile
      __syncthreads();
    } else {
#pragma unroll
      for (int q = 0; q < 4; ++q)
        out[((size_t)(b0 + lg * 4 + q) * NT + t) * NN + i] = rv[q];
    }
  }

  // r_final
#pragma unroll
  for (int q = 0; q < 4; ++q)
    out[(size_t)NBATCH * NT * NN + (size_t)(b0 + lg * 4 + q) * NN + i] = r[q];
}

extern "C" void kernel_launch(void* const* d_in, const int* in_sizes, int n_in,
                              void* d_out, int out_size, void* d_ws, size_t ws_size,
                              hipStream_t stream) {
  const float* u   = (const float*)d_in[0];
  const float* r0  = (const float*)d_in[1];
  const float* W   = (const float*)d_in[2];
  const float* Bm  = (const float*)d_in[3];
  const float* tau = (const float*)d_in[4];
  const float* ds  = (const float*)d_in[5];
  float* out = (float*)d_out;

  unsigned* obs32 = (unsigned*)d_ws;

  // zero both epoch-tagged buffers every call (tags restart at 1 -> deterministic)
  hipMemsetAsync(d_ws, 0, 2 * OBS32 * sizeof(unsigned), stream);

  rnn_step_all<<<dim3(NG * NSLOT), dim3(512), 0, stream>>>(u, r0, W, Bm, tau, ds,
                                                           out, obs32);
}